// Round 7
// baseline (25.445 us; speedup 1.0000x reference)
//
#include <hip/hip_runtime.h>

// Problem constants: B=2, N=512, M=50, P=2, L=9, D=32 -> flattened t/q dim = 576
#define BQ     2
#define NN     512
#define MM     50
#define TDIM   576
#define T4     144          // float4 per row
#define UNITS  (BQ * NN)    // 1024 units = one wave per (b,n) row

typedef float f4 __attribute__((ext_vector_type(4)));

// Math: the ERoPE rotation is orthogonal and identical for q,k at each
// (b,m,n,pair), so sum_t qr*kr = sum_t q*k (m-independent, trig-free):
//   out[b,m,n,:] = (q[b,n]·k[b,n] / 24) * grid_w[b,m] * v[b,n,:]
//
// One 64-lane wave per (b,n) row, owning ALL 50 m's (SPLIT=1): q/k/v are
// read exactly once (7.1 MB total — halves the t=0 read bubble vs SPLIT=2),
// no LDS, no barriers. v row in registers (144 float4 = 2.25/lane), then a
// pure stream of 150 coalesced stores.
__global__ void __launch_bounds__(256) erope_wave_kernel(
        const float* __restrict__ q,
        const float* __restrict__ k,
        const float* __restrict__ v,
        const float* __restrict__ w,
        float* __restrict__ out) {
    const int row  = blockIdx.x * 4 + (threadIdx.x >> 6);  // b*NN + n
    const int lane = threadIdx.x & 63;
    const int b    = row >> 9;           // NN = 512
    const int n    = row & (NN - 1);

    const f4* q4 = (const f4*)(q + (size_t)row * TDIM);
    const f4* k4 = (const f4*)(k + (size_t)row * TDIM);
    const f4* v4 = (const f4*)(v + (size_t)row * TDIM);

    // --- per-wave q·k dot + v row into registers (144 = 2*64 + 16) ---
    f4 a0 = q4[lane],      c0 = k4[lane];
    f4 a1 = q4[lane + 64], c1 = k4[lane + 64];
    f4 v0 = v4[lane],      v1 = v4[lane + 64];
    f4 v2 = {0.f, 0.f, 0.f, 0.f};
    float acc = a0.x*c0.x + a0.y*c0.y + a0.z*c0.z + a0.w*c0.w
              + a1.x*c1.x + a1.y*c1.y + a1.z*c1.z + a1.w*c1.w;
    if (lane < 16) {
        f4 a2 = q4[lane + 128], c2 = k4[lane + 128];
        v2 = v4[lane + 128];
        acc += a2.x*c2.x + a2.y*c2.y + a2.z*c2.z + a2.w*c2.w;
    }
    #pragma unroll
    for (int off = 32; off > 0; off >>= 1)
        acc += __shfl_xor(acc, off, 64);
    const float dval = acc * (1.0f / 24.0f);   // 1/sqrt(576)

    // --- stream 50 scaled copies of the v row ---
    const float* wp = w + b * MM;
    f4* ob = (f4*)out + ((size_t)(b * MM) * NN + n) * T4 + lane;
    const size_t mstride = (size_t)NN * T4;    // float4 stride between m's

    #pragma unroll 10
    for (int m = 0; m < MM; ++m) {
        const float s = dval * wp[m];
        f4* p = ob + (size_t)m * mstride;
        p[0]   = v0 * s;
        p[64]  = v1 * s;
        if (lane < 16) p[128] = v2 * s;
    }
}

extern "C" void kernel_launch(void* const* d_in, const int* in_sizes, int n_in,
                              void* d_out, int out_size, void* d_ws, size_t ws_size,
                              hipStream_t stream) {
    const float* q   = (const float*)d_in[0];   // [B,N,P,LQK,DQK]
    const float* k   = (const float*)d_in[1];
    const float* v   = (const float*)d_in[2];   // [B,N,P,LV,DV]
    // d_in[3]=pos, d_in[4]=grid_u, d_in[6]=theta unused: rotation cancels.
    const float* w   = (const float*)d_in[5];   // grid_w [B,M]
    float*       out = (float*)d_out;           // [B,M,N,P,LV,DV]

    erope_wave_kernel<<<UNITS / 4, 256, 0, stream>>>(q, k, v, w, out);
}